// Round 8
// baseline (515.188 us; speedup 1.0000x reference)
//
#include <hip/hip_runtime.h>
#include <hip/hip_bf16.h>

// B=64 batch, T=512 enc timesteps, E=1024 enc hidden, D=1024 dec hidden
// ALL inputs/outputs are FLOAT32 (per reference setup_inputs).
#define BB 64
#define TT 512
#define EE 1024
#define DD 1024

typedef __attribute__((ext_vector_type(8))) short s16x8;   // 8 bf16 MFMA A/B frag
typedef __attribute__((ext_vector_type(4))) float f32x4;   // MFMA C/D frag

#define AS1 __attribute__((address_space(1)))
#define AS3 __attribute__((address_space(3)))

__device__ __forceinline__ unsigned short f2bf(float f) {   // RNE, finite inputs
    unsigned int u = __builtin_bit_cast(unsigned int, f);
    u += 0x7FFF + ((u >> 16) & 1);
    return (unsigned short)(u >> 16);
}
__device__ __forceinline__ float tanh_fast(float x) {
    x = fminf(fmaxf(x, -15.f), 15.f);
    float e = __expf(2.f * x);
    return (e - 1.f) / (e + 1.f);
}

// Tile-order slot for chunk (row 0..127, g 0..7):  [8 bf16 chunks of 16B]
//   slot = (row>>4)*128 + (g>>2)*64 + (g&3)*16 + (row&15)
__device__ __forceinline__ int tile_slot(int row, int g) {
    return (row >> 4) * 128 + (g >> 2) * 64 + (g & 3) * 16 + (row & 15);
}

// ---------------------------------------------------------------------------
// enc f32 [32768,1024] -> encS bf16 tiled: tile (tm 0..255, tk 0..15) of
// 128 rows x 64 k stored as 1024 chunks in tile_slot order (16 KB/tile).
// grid = (256, 16), block = 256.
// ---------------------------------------------------------------------------
__global__ __launch_bounds__(256) void conv_encS_kernel(
    const float* __restrict__ enc, unsigned short* __restrict__ encS)
{
    __shared__ short tileL[1024 * 8];   // 16 KB
    const int tm  = blockIdx.x;
    const int tk  = blockIdx.y;
    const int tid = threadIdx.x;

#pragma unroll
    for (int it = 0; it < 4; ++it) {
        int cidx = it * 256 + tid;       // chunk id
        int row  = cidx >> 3;            // 0..127
        int g    = cidx & 7;             // 0..7
        const float* src = enc + (size_t)(tm * 128 + row) * 1024 + tk * 64 + g * 8;
        float4 v0 = ((const float4*)src)[0];
        float4 v1 = ((const float4*)src)[1];
        short c[8];
        c[0] = (short)f2bf(v0.x); c[1] = (short)f2bf(v0.y);
        c[2] = (short)f2bf(v0.z); c[3] = (short)f2bf(v0.w);
        c[4] = (short)f2bf(v1.x); c[5] = (short)f2bf(v1.y);
        c[6] = (short)f2bf(v1.z); c[7] = (short)f2bf(v1.w);
        *(s16x8*)&tileL[tile_slot(row, g) * 8] = *(s16x8*)c;
    }
    __syncthreads();
    unsigned short* dst = encS + ((size_t)tm * 16 + tk) * 8192;
#pragma unroll
    for (int it = 0; it < 4; ++it) {
        int s = it * 256 + tid;
        *(s16x8*)&dst[s * 8] = *(const s16x8*)&tileL[s * 8];
    }
}

// ---------------------------------------------------------------------------
// FUSED: blocks 0..255  -> conv_waS (Wa[:,1024:2048] f32 -> WaS bf16 tiled)
//        blocks 256..511 -> hproj (hp[f][b] = hidden[b,:].Wa[f,:1024] + ba[f])
// ---------------------------------------------------------------------------
__global__ __launch_bounds__(256) void prep_kernel(
    const float* __restrict__ Wa,       // [2048,2048]
    const float* __restrict__ hidden,   // [64,1024]
    const float* __restrict__ ba,       // [2048]
    unsigned short* __restrict__ WaS,   // tiled bf16
    float* __restrict__ hp)             // [2048*64]
{
    __shared__ float smem[8 * 1024];    // 32 KB (conv part uses first 16 KB as short[8192])
    const int bid = blockIdx.x;
    const int tid = threadIdx.x;

    if (bid < 256) {
        short* tileL = (short*)smem;    // 16 KB
        const int tn = bid & 15;
        const int tk = bid >> 4;
#pragma unroll
        for (int it = 0; it < 4; ++it) {
            int cidx = it * 256 + tid;
            int row  = cidx >> 3;            // f within tile
            int g    = cidx & 7;
            const float* src = Wa + (size_t)(tn * 128 + row) * 2048 + 1024 + tk * 64 + g * 8;
            float4 v0 = ((const float4*)src)[0];
            float4 v1 = ((const float4*)src)[1];
            short c[8];
            c[0] = (short)f2bf(v0.x); c[1] = (short)f2bf(v0.y);
            c[2] = (short)f2bf(v0.z); c[3] = (short)f2bf(v0.w);
            c[4] = (short)f2bf(v1.x); c[5] = (short)f2bf(v1.y);
            c[6] = (short)f2bf(v1.z); c[7] = (short)f2bf(v1.w);
            *(s16x8*)&tileL[tile_slot(row, g) * 8] = *(s16x8*)c;
        }
        __syncthreads();
        unsigned short* dst = WaS + ((size_t)tn * 16 + tk) * 8192;
#pragma unroll
        for (int it = 0; it < 4; ++it) {
            int s = it * 256 + tid;
            *(s16x8*)&dst[s * 8] = *(const s16x8*)&tileL[s * 8];
        }
    } else {
        const int lane = tid & 63;
        const int wave = tid >> 6;
        const int f0   = (bid - 256) * 8;
#pragma unroll
        for (int i = 0; i < 8; ++i) {
            int idx = i * 256 + tid;
            int fi  = idx >> 8;
            int c4  = idx & 255;
            ((float4*)smem)[idx] = *(const float4*)(Wa + (size_t)(f0 + fi) * 2048 + c4 * 4);
        }
        __syncthreads();
        for (int bi = 0; bi < 16; ++bi) {
            int b = wave * 16 + bi;
            float h[16];
#pragma unroll
            for (int j = 0; j < 16; ++j) h[j] = hidden[b * 1024 + lane + 64 * j];
#pragma unroll
            for (int fi = 0; fi < 8; ++fi) {
                float s = 0.f;
#pragma unroll
                for (int j = 0; j < 16; ++j) s += h[j] * smem[fi * 1024 + lane + 64 * j];
#pragma unroll
                for (int m = 32; m; m >>= 1) s += __shfl_xor(s, m);
                if (lane == 0) hp[(f0 + fi) * 64 + b] = s + ba[f0 + fi];
            }
        }
    }
}

// ---------------------------------------------------------------------------
// Fused e_proj GEMM (bf16 MFMA) + tanh + w2-dot -> scores_part[bn][b][t]
// 256x256 tile, 16 waves (4M x 4N, 64x64 each), 1024 threads, double-buffered
// LDS (round-7 structure, best measured 182 us). Epilogue now writes its
// (b,t) partial NON-atomically to scores_part (each element written once).
// grid = 1024 (XCD-swizzled, bn-fast), block = 1024.
// ---------------------------------------------------------------------------
__global__ __launch_bounds__(1024) void gemm_scores(
    const unsigned short* __restrict__ encS,  // tiled bf16 (ws), 256 x 16 tiles
    const unsigned short* __restrict__ WaS,   // tiled bf16 (ws), 16 x 16 tiles
    const float* __restrict__ hp,             // [2048*64] f32, f-major
    const float* __restrict__ w2,             // [2048] f32
    float* __restrict__ scoresP)              // [8][64][512] f32 partials
{
    __shared__ short sA[2][2][8192];   // [buf][mt] 16KB pre-swizzled tiles (64 KB)
    __shared__ short sB[2][2][8192];   // [buf][nt]                         (64 KB)
    __shared__ float rowAcc[256];

    const int tid  = threadIdx.x;
    const int bid  = blockIdx.x;
    const int w    = (bid & 7) * 128 + (bid >> 3);
    const int bm   = w >> 3;          // 0..127  (M/256)
    const int bn   = w & 7;           // 0..7    (N/256)
    const int lane = tid & 63;
    const int wave = tid >> 6;        // 0..15
    const int wm   = wave >> 2;       // 0..3  (M quarter)
    const int wn   = wave & 3;        // 0..3  (N quarter)
    const int c    = lane & 15;
    const int quad = lane >> 4;
    const int mt   = wm >> 1;           // A LDS tile for this wave
    const int mrow0 = (wm & 1) * 4;     // m16-row base within that tile
    const int nt   = wn >> 1;           // B LDS tile
    const int nrow0 = (wn & 1) * 4;

    f32x4 acc[4][4];
#pragma unroll
    for (int m = 0; m < 4; ++m)
#pragma unroll
        for (int n = 0; n < 4; ++n)
#pragma unroll
            for (int r = 0; r < 4; ++r) acc[m][n][r] = 0.f;

    const unsigned short* aT = encS + ((size_t)(bm * 2) * 16) * 8192;
    const unsigned short* bT = WaS  + ((size_t)(bn * 2) * 16) * 8192;

    auto STAGE_ALL = [&](int kt, int nb) {
#pragma unroll
        for (int t = 0; t < 2; ++t) {
            const unsigned short* sa = aT + ((size_t)(t * 16 + kt)) * 8192;
            __builtin_amdgcn_global_load_lds(
                (const AS1 void*)(sa + tid * 8),
                (AS3 void*)&sA[nb][t][tid * 8], 16, 0, 0);
            const unsigned short* sb = bT + ((size_t)(t * 16 + kt)) * 8192;
            __builtin_amdgcn_global_load_lds(
                (const AS1 void*)(sb + tid * 8),
                (AS3 void*)&sB[nb][t][tid * 8], 16, 0, 0);
        }
    };

    STAGE_ALL(0, 0);

    for (int kt = 0; kt < 16; ++kt) {
        const int cur = kt & 1;
        asm volatile("s_waitcnt vmcnt(0)" ::: "memory");
        __builtin_amdgcn_s_barrier();
        __builtin_amdgcn_sched_barrier(0);
        if (kt < 15) STAGE_ALL(kt + 1, cur ^ 1);

#pragma unroll
        for (int kk = 0; kk < 2; ++kk) {
            s16x8 aF[4], bF[4];
#pragma unroll
            for (int m = 0; m < 4; ++m)
                aF[m] = *(const s16x8*)
                    &sA[cur][mt][((mrow0 + m) * 128 + kk * 64 + lane) * 8];
#pragma unroll
            for (int n = 0; n < 4; ++n)
                bF[n] = *(const s16x8*)
                    &sB[cur][nt][((nrow0 + n) * 128 + kk * 64 + lane) * 8];

            __builtin_amdgcn_s_setprio(1);
#pragma unroll
            for (int m = 0; m < 4; ++m)
#pragma unroll
                for (int n = 0; n < 4; ++n)
                    acc[m][n] = __builtin_amdgcn_mfma_f32_16x16x32_bf16(
                        aF[m], bF[n], acc[m][n], 0, 0, 0);
            __builtin_amdgcn_s_setprio(0);
        }
        __builtin_amdgcn_sched_barrier(0);
        __builtin_amdgcn_s_barrier();
    }

    // Epilogue: rowAcc[row] = sum_f tanh(C + hp) * w2 over this block's 256 cols.
    if (tid < 256) rowAcc[tid] = 0.f;
    __syncthreads();

    float w2v[4];
#pragma unroll
    for (int n = 0; n < 4; ++n) w2v[n] = w2[bn * 256 + wn * 64 + n * 16 + c];

#pragma unroll
    for (int m = 0; m < 4; ++m) {
        int lrow0 = wm * 64 + m * 16 + quad * 4;        // local row, 4-aligned
        int b0    = lrow0 & 63;                          // batch base (bm*256 % 64 == 0)
        f32x4 hp4[4];
#pragma unroll
        for (int n = 0; n < 4; ++n)
            hp4[n] = *(const f32x4*)&hp[(bn * 256 + wn * 64 + n * 16 + c) * 64 + b0];
#pragma unroll
        for (int r = 0; r < 4; ++r) {
            float s = 0.f;
#pragma unroll
            for (int n = 0; n < 4; ++n)
                s += tanh_fast(acc[m][n][r] + hp4[n][r]) * w2v[n];
            s += __shfl_xor(s, 1);
            s += __shfl_xor(s, 2);
            s += __shfl_xor(s, 4);
            s += __shfl_xor(s, 8);
            if (c == 0) atomicAdd(&rowAcc[lrow0 + r], s);
        }
    }
    __syncthreads();
    if (tid < 256) {
        int b = tid & 63;                    // local row -> (b, t)
        int t = bm * 4 + (tid >> 6);
        scoresP[((size_t)bn * 64 + b) * 512 + t] = rowAcc[tid];   // written once
    }
}

// ---------------------------------------------------------------------------
// applied partials with INLINE softmax: each block (tc, b) first reduces
// scores_part over bn and computes softmax weights for row b (redundant per
// tc, trivial cost), then accumulates its 32-timestep chunk of applied.
// part[tc][b][e] = sum_{t in chunk tc} w[b,t]*enc[t,b,e]
// grid = (16 tc, 64 b), block = 256: 128 e-owners x 2 t-halves
// ---------------------------------------------------------------------------
__global__ __launch_bounds__(256) void applied_part_kernel(
    const float* __restrict__ enc,            // [T,B,E] f32
    const float* __restrict__ scoresP,        // [8][64][512] f32 partials
    float* __restrict__ part)                 // [16][64][1024]
{
    __shared__ float red[128 * 8];
    __shared__ float sw[512];
    __shared__ float red4[4];
    const int tc  = blockIdx.x;
    const int b   = blockIdx.y;
    const int tid = threadIdx.x;
    const int eo  = tid & 127;
    const int th  = tid >> 7;
    const int e0  = eo * 8;

    // ---- inline softmax over T for row b ----
    {
        const int t0 = tid * 2;
        float s0 = 0.f, s1 = 0.f;
#pragma unroll
        for (int bn = 0; bn < 8; ++bn) {
            const float* sp = scoresP + ((size_t)bn * 64 + b) * 512;
            s0 += sp[t0]; s1 += sp[t0 + 1];
        }
        float m = fmaxf(s0, s1);
#pragma unroll
        for (int o = 32; o; o >>= 1) m = fmaxf(m, __shfl_xor(m, o));
        if ((tid & 63) == 0) red4[tid >> 6] = m;
        __syncthreads();
        m = fmaxf(fmaxf(red4[0], red4[1]), fmaxf(red4[2], red4[3]));
        __syncthreads();                       // protect red4 before reuse
        float e0v = __expf(s0 - m), e1v = __expf(s1 - m);
        float ss = e0v + e1v;
#pragma unroll
        for (int o = 32; o; o >>= 1) ss += __shfl_xor(ss, o);
        if ((tid & 63) == 0) red4[tid >> 6] = ss;
        __syncthreads();
        float inv = 1.f / (red4[0] + red4[1] + red4[2] + red4[3]);
        sw[t0]     = e0v * inv;
        sw[t0 + 1] = e1v * inv;
        __syncthreads();
    }

    float a[8];
#pragma unroll
    for (int j = 0; j < 8; ++j) a[j] = 0.f;

    for (int it = 0; it < 16; ++it) {
        int t = tc * 32 + th * 16 + it;
        float wt = sw[t];
        const float* src = enc + ((size_t)(t * BB + b)) * EE + e0;
        float4 v0 = ((const float4*)src)[0];
        float4 v1 = ((const float4*)src)[1];
        a[0] += wt * v0.x; a[1] += wt * v0.y; a[2] += wt * v0.z; a[3] += wt * v0.w;
        a[4] += wt * v1.x; a[5] += wt * v1.y; a[6] += wt * v1.z; a[7] += wt * v1.w;
    }
    if (th == 1) {
#pragma unroll
        for (int j = 0; j < 8; ++j) red[eo * 8 + j] = a[j];
    }
    __syncthreads();
    if (th == 0) {
        float* dst = part + ((size_t)tc * 64 + b) * 1024 + e0;
#pragma unroll
        for (int j = 0; j < 8; ++j) dst[j] = a[j] + red[eo * 8 + j];
    }
}

// reduce 16 partials -> applied (output 1, f32) at out+65536
__global__ __launch_bounds__(256) void applied_reduce_kernel(
    const float* __restrict__ part, float* __restrict__ out_applied)
{
    int idx = blockIdx.x * 256 + threadIdx.x;
    float s = 0.f;
#pragma unroll
    for (int tc = 0; tc < 16; ++tc) s += part[tc * 65536 + idx];
    out_applied[idx] = s;
}

// ---------------------------------------------------------------------------
// out[b,d] = tanh(dec[b].Wc[d,:1024] + applied[b].Wc[d,1024:] + bc[d])
// Register-tiled: each wave computes an 8d x 8b output tile.
// grid = 256 blocks x 4 waves.
// ---------------------------------------------------------------------------
__global__ __launch_bounds__(256) void combine_kernel(
    const float* __restrict__ dec,       // [64,1024]
    const float* applied,                // [64,1024] (= out+65536)
    const float* __restrict__ Wc,        // [1024,2048]
    const float* __restrict__ bc,        // [1024]
    float* out0)                         // first 65536 of d_out
{
    const int gw   = blockIdx.x * 4 + (threadIdx.x >> 6);  // 0..1023
    const int lane = threadIdx.x & 63;
    const int d0   = (gw >> 3) * 8;      // 128 d-groups
    const int b0   = (gw & 7) * 8;       // 8 b-groups

    float acc[8][8];
#pragma unroll
    for (int dd = 0; dd < 8; ++dd)
#pragma unroll
        for (int bb = 0; bb < 8; ++bb) acc[dd][bb] = 0.f;

#pragma unroll
    for (int j = 0; j < 8; ++j) {
        float4 wv[8];
#pragma unroll
        for (int dd = 0; dd < 8; ++dd)
            wv[dd] = ((const float4*)(Wc + (size_t)(d0 + dd) * 2048))[j * 64 + lane];
        float4 cv[8];
        if (j < 4) {
#pragma unroll
            for (int bb = 0; bb < 8; ++bb)
                cv[bb] = ((const float4*)(dec + (size_t)(b0 + bb) * 1024))[j * 64 + lane];
        } else {
#pragma unroll
            for (int bb = 0; bb < 8; ++bb)
                cv[bb] = ((const float4*)(applied + (size_t)(b0 + bb) * 1024))[(j - 4) * 64 + lane];
        }
#pragma unroll
        for (int dd = 0; dd < 8; ++dd)
#pragma unroll
            for (int bb = 0; bb < 8; ++bb)
                acc[dd][bb] += wv[dd].x * cv[bb].x + wv[dd].y * cv[bb].y
                             + wv[dd].z * cv[bb].z + wv[dd].w * cv[bb].w;
    }

#pragma unroll
    for (int dd = 0; dd < 8; ++dd) {
#pragma unroll
        for (int bb = 0; bb < 8; ++bb) {
            float s = acc[dd][bb];
#pragma unroll
            for (int m = 32; m; m >>= 1) s += __shfl_xor(s, m);
            if (lane == 0)
                out0[(size_t)(b0 + bb) * DD + d0 + dd] = tanh_fast(s + bc[d0 + dd]);
        }
    }
}

// ---------------------------------------------------------------------------
extern "C" void kernel_launch(void* const* d_in, const int* in_sizes, int n_in,
                              void* d_out, int out_size, void* d_ws, size_t ws_size,
                              hipStream_t stream) {
    const float* hidden = (const float*)d_in[0]; // [64,1024]
    const float* dec    = (const float*)d_in[1]; // [64,1024]
    const float* enc    = (const float*)d_in[2]; // [512,64,1024]
    const float* Wa     = (const float*)d_in[3]; // [2048,2048]
    const float* ba     = (const float*)d_in[4]; // [2048]
    const float* w2     = (const float*)d_in[5]; // [2048]
    // d_in[6] = b2: uniform shift of scores -> softmax-invariant, unused.
    const float* Wc     = (const float*)d_in[7]; // [1024,2048]
    const float* bc     = (const float*)d_in[8]; // [1024]
    float* out = (float*)d_out;                  // [64*1024 out | 64*1024 applied]

    unsigned short* encS = (unsigned short*)d_ws;               // 33554432 bf16 (tiled)
    unsigned short* WaS  = encS + (size_t)33554432;             //  2097152 bf16 (tiled)
    float* hp      = (float*)(WaS + (size_t)2097152);           //   131072 f32
    float* scoresP = hp + 131072;                               //   262144 f32 [8][64][512]
    float* part    = scoresP + 262144;                          //  1048576 f32

    dim3 gc(256, 16);
    conv_encS_kernel<<<gc, 256, 0, stream>>>(enc, encS);
    prep_kernel<<<512, 256, 0, stream>>>(Wa, hidden, ba, WaS, hp);
    gemm_scores<<<1024, 1024, 0, stream>>>(encS, WaS, hp, w2, scoresP);
    dim3 g3(16, 64);
    applied_part_kernel<<<g3, 256, 0, stream>>>(enc, scoresP, part);
    applied_reduce_kernel<<<256, 256, 0, stream>>>(part, out + BB * DD);
    combine_kernel<<<256, 256, 0, stream>>>(dec, out + BB * DD, Wc, bc, out);
}

// Round 9
// 506.976 us; speedup vs baseline: 1.0162x; 1.0162x over previous
//
#include <hip/hip_runtime.h>
#include <hip/hip_bf16.h>

// B=64 batch, T=512 enc timesteps, E=1024 enc hidden, D=1024 dec hidden
// ALL inputs/outputs are FLOAT32 (per reference setup_inputs).
#define BB 64
#define TT 512
#define EE 1024
#define DD 1024

typedef __attribute__((ext_vector_type(8))) short s16x8;   // 8 bf16 MFMA A/B frag
typedef __attribute__((ext_vector_type(4))) float f32x4;   // MFMA C/D frag

#define AS1 __attribute__((address_space(1)))
#define AS3 __attribute__((address_space(3)))

__device__ __forceinline__ unsigned short f2bf(float f) {   // RNE, finite inputs
    unsigned int u = __builtin_bit_cast(unsigned int, f);
    u += 0x7FFF + ((u >> 16) & 1);
    return (unsigned short)(u >> 16);
}
__device__ __forceinline__ float tanh_fast(float x) {
    x = fminf(fmaxf(x, -15.f), 15.f);
    float e = __expf(2.f * x);
    return (e - 1.f) / (e + 1.f);
}

// Tile-order slot for chunk (row 0..127, g 0..7):  [8 bf16 chunks of 16B]
//   slot = (row>>4)*128 + (g>>2)*64 + (g&3)*16 + (row&15)
// Fragment reads are lane-linear: slot = m16*128 + kk*64 + lane -> lane holds
//   A[row=m16*16+(lane&15)][k=kk*32+(lane>>4)*8 ..+8]
__device__ __forceinline__ int tile_slot(int row, int g) {
    return (row >> 4) * 128 + (g >> 2) * 64 + (g & 3) * 16 + (row & 15);
}

// ---------------------------------------------------------------------------
// FUSED: blocks 0..255  -> conv_waS (Wa[:,1024:2048] f32 -> WaS bf16 tiled)
//        blocks 256..511 -> hproj (hp[f][b] = hidden[b,:].Wa[f,:1024] + ba[f])
// ---------------------------------------------------------------------------
__global__ __launch_bounds__(256) void prep_kernel(
    const float* __restrict__ Wa,       // [2048,2048]
    const float* __restrict__ hidden,   // [64,1024]
    const float* __restrict__ ba,       // [2048]
    unsigned short* __restrict__ WaS,   // tiled bf16
    float* __restrict__ hp)             // [2048*64]
{
    __shared__ float smem[8 * 1024];    // 32 KB (conv part uses first 16 KB as short[8192])
    const int bid = blockIdx.x;
    const int tid = threadIdx.x;

    if (bid < 256) {
        short* tileL = (short*)smem;    // 16 KB
        const int tn = bid & 15;
        const int tk = bid >> 4;
#pragma unroll
        for (int it = 0; it < 4; ++it) {
            int cidx = it * 256 + tid;
            int row  = cidx >> 3;            // f within tile
            int g    = cidx & 7;
            const float* src = Wa + (size_t)(tn * 128 + row) * 2048 + 1024 + tk * 64 + g * 8;
            float4 v0 = ((const float4*)src)[0];
            float4 v1 = ((const float4*)src)[1];
            short c[8];
            c[0] = (short)f2bf(v0.x); c[1] = (short)f2bf(v0.y);
            c[2] = (short)f2bf(v0.z); c[3] = (short)f2bf(v0.w);
            c[4] = (short)f2bf(v1.x); c[5] = (short)f2bf(v1.y);
            c[6] = (short)f2bf(v1.z); c[7] = (short)f2bf(v1.w);
            *(s16x8*)&tileL[tile_slot(row, g) * 8] = *(s16x8*)c;
        }
        __syncthreads();
        unsigned short* dst = WaS + ((size_t)tn * 16 + tk) * 8192;
#pragma unroll
        for (int it = 0; it < 4; ++it) {
            int s = it * 256 + tid;
            *(s16x8*)&dst[s * 8] = *(const s16x8*)&tileL[s * 8];
        }
    } else {
        const int lane = tid & 63;
        const int wave = tid >> 6;
        const int f0   = (bid - 256) * 8;
#pragma unroll
        for (int i = 0; i < 8; ++i) {
            int idx = i * 256 + tid;
            int fi  = idx >> 8;
            int c4  = idx & 255;
            ((float4*)smem)[idx] = *(const float4*)(Wa + (size_t)(f0 + fi) * 2048 + c4 * 4);
        }
        __syncthreads();
        for (int bi = 0; bi < 16; ++bi) {
            int b = wave * 16 + bi;
            float h[16];
#pragma unroll
            for (int j = 0; j < 16; ++j) h[j] = hidden[b * 1024 + lane + 64 * j];
#pragma unroll
            for (int fi = 0; fi < 8; ++fi) {
                float s = 0.f;
#pragma unroll
                for (int j = 0; j < 16; ++j) s += h[j] * smem[fi * 1024 + lane + 64 * j];
#pragma unroll
                for (int m = 32; m; m >>= 1) s += __shfl_xor(s, m);
                if (lane == 0) hp[(f0 + fi) * 64 + b] = s + ba[f0 + fi];
            }
        }
    }
}

// ---------------------------------------------------------------------------
// Fused e_proj GEMM (bf16 MFMA) + tanh + w2-dot -> scores_part[bn][b][t]
// 256x256 tile, 16 waves (4M x 4N, 64x64 each), 1024 threads, double-buffered
// LDS. A-tiles now staged DIRECTLY from f32 enc (conv_encS kernel deleted):
// per thread: 4x global_load_dwordx4 (coalesced 256B segments), 16x f2bf,
// 2x ds_write_b128 at tile_slot (8 disjoint 128B bank-rows/wave: conflict-
// free; LDS image identical to the old pre-tiled encS). T14 split: A-loads
// issued at tile top, vmcnt(2)-waited AFTER the tile's MFMA, written to the
// next buffer at tile end. B still via global_load_lds. One barrier/K-tile.
// grid = 1024 (XCD-swizzled, bn-fast), block = 1024.
// ---------------------------------------------------------------------------
__global__ __launch_bounds__(1024) void gemm_scores(
    const float* __restrict__ enc,            // [32768,1024] f32 (A source)
    const unsigned short* __restrict__ WaS,   // tiled bf16 (ws), 16 x 16 tiles
    const float* __restrict__ hp,             // [2048*64] f32, f-major
    const float* __restrict__ w2,             // [2048] f32
    float* __restrict__ scoresP)              // [8][64][512] f32 partials
{
    __shared__ short sA[2][2][8192];   // [buf][mt] 16KB tiles (64 KB)
    __shared__ short sB[2][2][8192];   // [buf][nt]            (64 KB)
    __shared__ float rowAcc[256];

    const int tid  = threadIdx.x;
    const int bid  = blockIdx.x;
    const int w    = (bid & 7) * 128 + (bid >> 3);
    const int bm   = w >> 3;          // 0..127  (M/256)
    const int bn   = w & 7;           // 0..7    (N/256)
    const int lane = tid & 63;
    const int wave = tid >> 6;        // 0..15
    const int wm   = wave >> 2;       // 0..3  (M quarter)
    const int wn   = wave & 3;        // 0..3  (N quarter)
    const int c    = lane & 15;
    const int quad = lane >> 4;
    const int mt   = wm >> 1;           // A LDS tile for this wave
    const int mrow0 = (wm & 1) * 4;     // m16-row base within that tile
    const int nt   = wn >> 1;           // B LDS tile
    const int nrow0 = (wn & 1) * 4;

    // A-staging geometry: thread stages chunk (arow, ag) of BOTH A tiles.
    const int arow  = tid >> 3;         // 0..127
    const int ag    = tid & 7;          // 0..7
    const int aslot = tile_slot(arow, ag) * 8;
    const float* aBase = enc + ((size_t)(bm * 256) + arow) * 1024 + ag * 8;

    f32x4 acc[4][4];
#pragma unroll
    for (int m = 0; m < 4; ++m)
#pragma unroll
        for (int n = 0; n < 4; ++n)
#pragma unroll
            for (int r = 0; r < 4; ++r) acc[m][n][r] = 0.f;

    const unsigned short* bT = WaS + ((size_t)(bn * 2) * 16) * 8192;

    float4 pa[2][2];   // in-flight A chunks (reg-staged), 16 VGPR

    auto A_LOAD = [&](int kt) {
#pragma unroll
        for (int t = 0; t < 2; ++t) {
            const float* s = aBase + (size_t)t * 131072 + kt * 64;
            pa[t][0] = ((const float4*)s)[0];
            pa[t][1] = ((const float4*)s)[1];
        }
    };
    auto A_WRITE = [&](int nb) {
#pragma unroll
        for (int t = 0; t < 2; ++t) {
            short cv[8];
            cv[0] = (short)f2bf(pa[t][0].x); cv[1] = (short)f2bf(pa[t][0].y);
            cv[2] = (short)f2bf(pa[t][0].z); cv[3] = (short)f2bf(pa[t][0].w);
            cv[4] = (short)f2bf(pa[t][1].x); cv[5] = (short)f2bf(pa[t][1].y);
            cv[6] = (short)f2bf(pa[t][1].z); cv[7] = (short)f2bf(pa[t][1].w);
            *(s16x8*)&sA[nb][t][aslot] = *(s16x8*)cv;
        }
    };
    auto B_STAGE = [&](int kt, int nb) {
#pragma unroll
        for (int t = 0; t < 2; ++t) {
            const unsigned short* sb = bT + ((size_t)(t * 16 + kt)) * 8192;
            __builtin_amdgcn_global_load_lds(
                (const AS1 void*)(sb + tid * 8),
                (AS3 void*)&sB[nb][t][tid * 8], 16, 0, 0);
        }
    };

    // prologue: stage tile 0 into buffer 0
    A_LOAD(0);
    B_STAGE(0, 0);
    A_WRITE(0);                         // compiler waits the A-loads; B flies

    for (int kt = 0; kt < 16; ++kt) {
        const int cur = kt & 1;
        // B gload_lds for kt (issued one tile ago) + all ds_writes must land.
        asm volatile("s_waitcnt vmcnt(0)" ::: "memory");
        asm volatile("s_waitcnt lgkmcnt(0)" ::: "memory");
        __builtin_amdgcn_s_barrier();
        __builtin_amdgcn_sched_barrier(0);

        if (kt < 15) {
            A_LOAD(kt + 1);             // 4 global loads, waited after compute
            B_STAGE(kt + 1, cur ^ 1);   // 2 gload_lds, waited at next tile top
        }

#pragma unroll
        for (int kk = 0; kk < 2; ++kk) {
            s16x8 aF[4], bF[4];
#pragma unroll
            for (int m = 0; m < 4; ++m)
                aF[m] = *(const s16x8*)
                    &sA[cur][mt][((mrow0 + m) * 128 + kk * 64 + lane) * 8];
#pragma unroll
            for (int n = 0; n < 4; ++n)
                bF[n] = *(const s16x8*)
                    &sB[cur][nt][((nrow0 + n) * 128 + kk * 64 + lane) * 8];

            __builtin_amdgcn_s_setprio(1);
#pragma unroll
            for (int m = 0; m < 4; ++m)
#pragma unroll
                for (int n = 0; n < 4; ++n)
                    acc[m][n] = __builtin_amdgcn_mfma_f32_16x16x32_bf16(
                        aF[m], bF[n], acc[m][n], 0, 0, 0);
            __builtin_amdgcn_s_setprio(0);
        }

        if (kt < 15) {
            // A-loads for kt+1 were covered by this tile's compute.
            asm volatile("s_waitcnt vmcnt(2)" ::: "memory");
            __builtin_amdgcn_sched_barrier(0);
            A_WRITE(cur ^ 1);           // into the buffer kt+1 will read
        }
    }

    // Epilogue: rowAcc[row] = sum_f tanh(C + hp) * w2 over this block's 256 cols.
    __syncthreads();
    if (tid < 256) rowAcc[tid] = 0.f;
    __syncthreads();

    float w2v[4];
#pragma unroll
    for (int n = 0; n < 4; ++n) w2v[n] = w2[bn * 256 + wn * 64 + n * 16 + c];

#pragma unroll
    for (int m = 0; m < 4; ++m) {
        int lrow0 = wm * 64 + m * 16 + quad * 4;        // local row, 4-aligned
        int b0    = lrow0 & 63;                          // batch base (bm*256 % 64 == 0)
        f32x4 hp4[4];
#pragma unroll
        for (int n = 0; n < 4; ++n)
            hp4[n] = *(const f32x4*)&hp[(bn * 256 + wn * 64 + n * 16 + c) * 64 + b0];
#pragma unroll
        for (int r = 0; r < 4; ++r) {
            float s = 0.f;
#pragma unroll
            for (int n = 0; n < 4; ++n)
                s += tanh_fast(acc[m][n][r] + hp4[n][r]) * w2v[n];
            s += __shfl_xor(s, 1);
            s += __shfl_xor(s, 2);
            s += __shfl_xor(s, 4);
            s += __shfl_xor(s, 8);
            if (c == 0) atomicAdd(&rowAcc[lrow0 + r], s);
        }
    }
    __syncthreads();
    if (tid < 256) {
        int b = tid & 63;                    // local row -> (b, t)
        int t = bm * 4 + (tid >> 6);
        scoresP[((size_t)bn * 64 + b) * 512 + t] = rowAcc[tid];   // written once
    }
}

// ---------------------------------------------------------------------------
// applied partials with INLINE softmax: each block (tc, b) first reduces
// scores_part over bn and computes softmax weights for row b (redundant per
// tc, trivial cost), then accumulates its 32-timestep chunk of applied.
// part[tc][b][e] = sum_{t in chunk tc} w[b,t]*enc[t,b,e]
// grid = (16 tc, 64 b), block = 256: 128 e-owners x 2 t-halves
// ---------------------------------------------------------------------------
__global__ __launch_bounds__(256) void applied_part_kernel(
    const float* __restrict__ enc,            // [T,B,E] f32
    const float* __restrict__ scoresP,        // [8][64][512] f32 partials
    float* __restrict__ part)                 // [16][64][1024]
{
    __shared__ float red[128 * 8];
    __shared__ float sw[512];
    __shared__ float red4[4];
    const int tc  = blockIdx.x;
    const int b   = blockIdx.y;
    const int tid = threadIdx.x;
    const int eo  = tid & 127;
    const int th  = tid >> 7;
    const int e0  = eo * 8;

    // ---- inline softmax over T for row b ----
    {
        const int t0 = tid * 2;
        float s0 = 0.f, s1 = 0.f;
#pragma unroll
        for (int bn = 0; bn < 8; ++bn) {
            const float* sp = scoresP + ((size_t)bn * 64 + b) * 512;
            s0 += sp[t0]; s1 += sp[t0 + 1];
        }
        float m = fmaxf(s0, s1);
#pragma unroll
        for (int o = 32; o; o >>= 1) m = fmaxf(m, __shfl_xor(m, o));
        if ((tid & 63) == 0) red4[tid >> 6] = m;
        __syncthreads();
        m = fmaxf(fmaxf(red4[0], red4[1]), fmaxf(red4[2], red4[3]));
        __syncthreads();                       // protect red4 before reuse
        float e0v = __expf(s0 - m), e1v = __expf(s1 - m);
        float ss = e0v + e1v;
#pragma unroll
        for (int o = 32; o; o >>= 1) ss += __shfl_xor(ss, o);
        if ((tid & 63) == 0) red4[tid >> 6] = ss;
        __syncthreads();
        float inv = 1.f / (red4[0] + red4[1] + red4[2] + red4[3]);
        sw[t0]     = e0v * inv;
        sw[t0 + 1] = e1v * inv;
        __syncthreads();
    }

    float a[8];
#pragma unroll
    for (int j = 0; j < 8; ++j) a[j] = 0.f;

    for (int it = 0; it < 16; ++it) {
        int t = tc * 32 + th * 16 + it;
        float wt = sw[t];
        const float* src = enc + ((size_t)(t * BB + b)) * EE + e0;
        float4 v0 = ((const float4*)src)[0];
        float4 v1 = ((const float4*)src)[1];
        a[0] += wt * v0.x; a[1] += wt * v0.y; a[2] += wt * v0.z; a[3] += wt * v0.w;
        a[4] += wt * v1.x; a[5] += wt * v1.y; a[6] += wt * v1.z; a[7] += wt * v1.w;
    }
    if (th == 1) {
#pragma unroll
        for (int j = 0; j < 8; ++j) red[eo * 8 + j] = a[j];
    }
    __syncthreads();
    if (th == 0) {
        float* dst = part + ((size_t)tc * 64 + b) * 1024 + e0;
#pragma unroll
        for (int j = 0; j < 8; ++j) dst[j] = a[j] + red[eo * 8 + j];
    }
}

// reduce 16 partials -> applied (output 1, f32) at out+65536
__global__ __launch_bounds__(256) void applied_reduce_kernel(
    const float* __restrict__ part, float* __restrict__ out_applied)
{
    int idx = blockIdx.x * 256 + threadIdx.x;
    float s = 0.f;
#pragma unroll
    for (int tc = 0; tc < 16; ++tc) s += part[tc * 65536 + idx];
    out_applied[idx] = s;
}

// ---------------------------------------------------------------------------
// out[b,d] = tanh(dec[b].Wc[d,:1024] + applied[b].Wc[d,1024:] + bc[d])
// Register-tiled: each wave computes an 8d x 8b output tile.
// grid = 256 blocks x 4 waves.
// ---------------------------------------------------------------------------
__global__ __launch_bounds__(256) void combine_kernel(
    const float* __restrict__ dec,       // [64,1024]
    const float* applied,                // [64,1024] (= out+65536)
    const float* __restrict__ Wc,        // [1024,2048]
    const float* __restrict__ bc,        // [1024]
    float* out0)                         // first 65536 of d_out
{
    const int gw   = blockIdx.x * 4 + (threadIdx.x >> 6);  // 0..1023
    const int lane = threadIdx.x & 63;
    const int d0   = (gw >> 3) * 8;      // 128 d-groups
    const int b0   = (gw & 7) * 8;       // 8 b-groups

    float acc[8][8];
#pragma unroll
    for (int dd = 0; dd < 8; ++dd)
#pragma unroll
        for (int bb = 0; bb < 8; ++bb) acc[dd][bb] = 0.f;

#pragma unroll
    for (int j = 0; j < 8; ++j) {
        float4 wv[8];
#pragma unroll
        for (int dd = 0; dd < 8; ++dd)
            wv[dd] = ((const float4*)(Wc + (size_t)(d0 + dd) * 2048))[j * 64 + lane];
        float4 cv[8];
        if (j < 4) {
#pragma unroll
            for (int bb = 0; bb < 8; ++bb)
                cv[bb] = ((const float4*)(dec + (size_t)(b0 + bb) * 1024))[j * 64 + lane];
        } else {
#pragma unroll
            for (int bb = 0; bb < 8; ++bb)
                cv[bb] = ((const float4*)(applied + (size_t)(b0 + bb) * 1024))[(j - 4) * 64 + lane];
        }
#pragma unroll
        for (int dd = 0; dd < 8; ++dd)
#pragma unroll
            for (int bb = 0; bb < 8; ++bb)
                acc[dd][bb] += wv[dd].x * cv[bb].x + wv[dd].y * cv[bb].y
                             + wv[dd].z * cv[bb].z + wv[dd].w * cv[bb].w;
    }

#pragma unroll
    for (int dd = 0; dd < 8; ++dd) {
#pragma unroll
        for (int bb = 0; bb < 8; ++bb) {
            float s = acc[dd][bb];
#pragma unroll
            for (int m = 32; m; m >>= 1) s += __shfl_xor(s, m);
            if (lane == 0)
                out0[(size_t)(b0 + bb) * DD + d0 + dd] = tanh_fast(s + bc[d0 + dd]);
        }
    }
}

// ---------------------------------------------------------------------------
extern "C" void kernel_launch(void* const* d_in, const int* in_sizes, int n_in,
                              void* d_out, int out_size, void* d_ws, size_t ws_size,
                              hipStream_t stream) {
    const float* hidden = (const float*)d_in[0]; // [64,1024]
    const float* dec    = (const float*)d_in[1]; // [64,1024]
    const float* enc    = (const float*)d_in[2]; // [512,64,1024]
    const float* Wa     = (const float*)d_in[3]; // [2048,2048]
    const float* ba     = (const float*)d_in[4]; // [2048]
    const float* w2     = (const float*)d_in[5]; // [2048]
    // d_in[6] = b2: uniform shift of scores -> softmax-invariant, unused.
    const float* Wc     = (const float*)d_in[7]; // [1024,2048]
    const float* bc     = (const float*)d_in[8]; // [1024]
    float* out = (float*)d_out;                  // [64*1024 out | 64*1024 applied]

    unsigned short* WaS = (unsigned short*)d_ws;                //  2097152 bf16 (tiled)
    float* hp      = (float*)(WaS + (size_t)2097152);           //   131072 f32
    float* scoresP = hp + 131072;                               //   262144 f32 [8][64][512]
    float* part    = scoresP + 262144;                          //  1048576 f32

    prep_kernel<<<512, 256, 0, stream>>>(Wa, hidden, ba, WaS, hp);
    gemm_scores<<<1024, 1024, 0, stream>>>(enc, WaS, hp, w2, scoresP);
    dim3 g3(16, 64);
    applied_part_kernel<<<g3, 256, 0, stream>>>(enc, scoresP, part);
    applied_reduce_kernel<<<256, 256, 0, stream>>>(part, out + BB * DD);
    combine_kernel<<<256, 256, 0, stream>>>(dec, out + BB * DD, Wc, bc, out);
}